// Round 7
// baseline (853.026 us; speedup 1.0000x reference)
//
#include <hip/hip_runtime.h>
#include <hip/hip_bf16.h>
#include <hip/hip_cooperative_groups.h>

namespace cg = cooperative_groups;

// ---------------------------------------------------------------------------
// Attention_14929306321432 : (q+pe)@Wq+bq, (k+pe)@Wk+bk, v@Wv+bv,
// causal MHA (H=16, dh=64), out @ Wo + bo.   INPUTS fp32, OUTPUT fp32.
// R13: 327us FAILED - parity-split attn spilled (VGPR 64, WRITE 64MB scratch).
// R14: (a) attn reverted to R10 proven core (73.6us, 16x16, Ps wave-private).
//      (b) MEGAKERNEL: all 4 stages in ONE cooperative launch with
//          grid.sync() between - across R10-R13 the non-attn pool held at
//          ~237us while every non-attn dispatch measured <76us -> ~100us of
//          inter-dispatch gaps.  Grid 512x512thr, 64KB LDS, 2 blk/CU
//          co-resident.  attn stage: 2x256-thr groups per block, SAME px
//          per block (different bh) so block barriers have equal trips.
//      (c) runtime fallback to 4-launch path if cooperative launch errors.
// ws tiers: 104MB mega/fused | 88MB | 50MB fallback.
// ---------------------------------------------------------------------------

typedef __bf16 bf16_t;
typedef bf16_t bf16x8 __attribute__((ext_vector_type(8)));
typedef bf16_t bf16x4 __attribute__((ext_vector_type(4)));
typedef float  f32x4  __attribute__((ext_vector_type(4)));

#define MFMA_16x16x32(a, b, c) __builtin_amdgcn_mfma_f32_16x16x32_bf16((a), (b), (c), 0, 0, 0)

constexpr int Lc = 2048, Dc = 1024;
constexpr int Mc = 8192;
constexpr size_t WSZ_E = (size_t)Dc * Dc;       // WT segment stride (elements)
// 0.125 (1/sqrt(dh)) * log2(e): softmax runs in exp2 domain.
#define QSCALE 0.18033688011112042f

// async global->LDS DMA, 16B per lane.  LDS dest is wave-uniform base +
// lane*16 (HW rule) -> swizzle must live in the per-lane GLOBAL address.
__device__ __forceinline__ void gload16(const void* g, void* l) {
  __builtin_amdgcn_global_load_lds(
      (const __attribute__((address_space(1))) void*)g,
      (__attribute__((address_space(3))) void*)l, 16, 0, 0);
}

// ---------------------------------------------------------------------------
// qkv prep body: Aq = bf16(q+pe), Ak = bf16(k+pe), (DO_V) Av = bf16(v).
// ---------------------------------------------------------------------------
template <bool DO_V>
__device__ __forceinline__ void qkv_prep_body(
    const float* q, const float* k, const float* v,
    bf16_t* Aq, bf16_t* Ak, bf16_t* Av, int id) {
  int row = id >> 7;                              // 0 .. 8191
  int c   = (id & 127) * 8;                       // col 0..1016
  int pos = row & (Lc - 1);
  float period = __expf(-(float)(c >> 1) * 0.017988946039015984f);
  const float ratio = 0.98217189f;                // exp(-ln(1e4)/512)
  float pe8[8];
#pragma unroll
  for (int j = 0; j < 4; ++j) {
    float rev = ((float)pos * period) * 0.15915494309189535f;
    float rf = rev - floorf(rev);                 // v_fract
    pe8[2 * j]     = __builtin_amdgcn_sinf(rf);   // sin(2*pi*rf)
    pe8[2 * j + 1] = __builtin_amdgcn_cosf(rf);
    period *= ratio;
  }
  size_t off = (size_t)row * Dc + c;
  f32x4 q0 = *(const f32x4*)&q[off], q1 = *(const f32x4*)&q[off + 4];
  f32x4 k0 = *(const f32x4*)&k[off], k1 = *(const f32x4*)&k[off + 4];
  bf16x8 aq, ak;
#pragma unroll
  for (int e = 0; e < 4; ++e) {
    aq[e]     = (bf16_t)(q0[e] + pe8[e]);
    aq[4 + e] = (bf16_t)(q1[e] + pe8[4 + e]);
    ak[e]     = (bf16_t)(k0[e] + pe8[e]);
    ak[4 + e] = (bf16_t)(k1[e] + pe8[4 + e]);
  }
  *(bf16x8*)&Aq[off] = aq;
  *(bf16x8*)&Ak[off] = ak;
  if (DO_V) {
    f32x4 v0 = *(const f32x4*)&v[off], v1 = *(const f32x4*)&v[off + 4];
    bf16x8 av;
#pragma unroll
    for (int e = 0; e < 4; ++e) { av[e] = (bf16_t)v0[e]; av[4 + e] = (bf16_t)v1[e]; }
    *(bf16x8*)&Av[off] = av;
  }
}

template <bool DO_V>
__global__ __launch_bounds__(256)
void qkv_prep_kernel(const float* __restrict__ q, const float* __restrict__ k,
                     const float* __restrict__ v, bf16_t* __restrict__ Aq,
                     bf16_t* __restrict__ Ak, bf16_t* __restrict__ Av) {
  qkv_prep_body<DO_V>(q, k, v, Aq, Ak, Av, blockIdx.x * 256 + threadIdx.x);
}

// ---------------------------------------------------------------------------
// Wt[n][k] = bf16(W[k][n])  (1024x1024), 64x64 tile; tile = float[64*65].
// ---------------------------------------------------------------------------
__device__ __forceinline__ void w_prep_body(const float* W, bf16_t* Wt, int tid,
                                            int blk, float* tile) {
  int k0 = (blk >> 4) * 64, n0 = (blk & 15) * 64;
  int tc = tid & 63, tr = tid >> 6;
#pragma unroll
  for (int j = 0; j < 16; ++j) {
    int r = j * 4 + tr;
    tile[r * 65 + tc] = W[(size_t)(k0 + r) * Dc + n0 + tc];
  }
  __syncthreads();
#pragma unroll
  for (int j = 0; j < 16; ++j) {
    int r = j * 4 + tr;
    Wt[(size_t)(n0 + r) * Dc + k0 + tc] = (bf16_t)tile[tc * 65 + r];
  }
}

__global__ __launch_bounds__(256)
void w_prep_kernel(const float* __restrict__ W, bf16_t* __restrict__ Wt) {
  __shared__ float tile[4160];
  w_prep_body(W, Wt, threadIdx.x, blockIdx.x, tile);
}

// qkv prep (4096 blocks) + all 4 W transposes (1024 blocks) in ONE launch.
__global__ __launch_bounds__(256)
void prep_fused_kernel(const float* __restrict__ q, const float* __restrict__ k,
                       const float* __restrict__ v, bf16_t* __restrict__ Aq,
                       bf16_t* __restrict__ Ak, bf16_t* __restrict__ Av,
                       const float* __restrict__ W0, const float* __restrict__ W1,
                       const float* __restrict__ W2, const float* __restrict__ W3,
                       bf16_t* __restrict__ Wt) {
  __shared__ float tile[4160];
  if (blockIdx.x >= 4096) {
    int bb = blockIdx.x - 4096;
    int sel = bb >> 8;
    const float* W = (sel == 0) ? W0 : (sel == 1) ? W1 : (sel == 2) ? W2 : W3;
    w_prep_body(W, Wt + (size_t)sel * WSZ_E, threadIdx.x, bb & 255, tile);
    return;
  }
  qkv_prep_body<true>(q, k, v, Aq, Ak, Av, blockIdx.x * 256 + threadIdx.x);
}

// ---------------------------------------------------------------------------
// GEMM body: C = A @ W + bias (then *scale).  A bf16 [M][K], Wt bf16 [N][K].
// 128x128 tile, BK=64, 512 thr = 8 waves (4m x 2n; wave 32x64).
// Double-buffered: prefetch tile t+1 via global_load_lds under compute of t;
// counted s_waitcnt vmcnt(4) + raw s_barrier.  16B slots XOR-swizzled in the
// global source and on the ds_read_b128 side -> conflict-free.
// XCD swizzle on bid (0..511).  smem = 32768 bf16 (64KB).
// TRANS: write bf16 C^T per (b, col): C[(b*1024+n)*2048 + pos].
// ---------------------------------------------------------------------------
template <bool TRANS, typename OutT>
__device__ __forceinline__ void gemm_body(
    const bf16_t* __restrict__ A, const bf16_t* __restrict__ Wt,
    const float* __restrict__ bias, OutT* __restrict__ C, float scale,
    int bid, int t, bf16_t* __restrict__ smem) {
  constexpr int K = 1024, N = 1024, LDS_T = 136;
  int xcd = bid & 7, slot = bid >> 3;             // slot 0..63
  int m0 = (xcd * 8 + (slot >> 3)) * 128;
  int n0 = (slot & 7) * 128;
  int lane = t & 63, w = t >> 6;                  // w 0..7
  int l16 = lane & 15, lq = lane >> 4;
  int wm = (w >> 1) * 32, wn = (w & 1) * 64;
  int srow = lane >> 3;                           // row within 8-row DMA group
  int scol = ((lane & 7) ^ srow) << 3;            // inverse-swizzled src col
  int swz = l16 & 7;                              // read-side swizzle key
  f32x4 acc[2][4] = {};

  auto STAGE = [&](int c, int k0) {
    bf16_t* Ash = &smem[c * 16384];
    bf16_t* Bsh = Ash + 8192;
#pragma unroll
    for (int j = 0; j < 2; ++j) {
      int r8 = (w * 2 + j) * 8;                   // wave-uniform LDS base row
      gload16(&A[(size_t)(m0 + r8 + srow) * K + k0 + scol], &Ash[r8 * 64]);
      gload16(&Wt[(size_t)(n0 + r8 + srow) * K + k0 + scol], &Bsh[r8 * 64]);
    }
  };

  STAGE(0, 0);
  int c = 0;
#pragma unroll 1
  for (int ti = 0; ti < 16; ++ti) {
    if (ti < 15) {
      STAGE(c ^ 1, (ti + 1) * 64);
      asm volatile("s_waitcnt vmcnt(4)" ::: "memory");  // tile ti landed
    } else {
      asm volatile("s_waitcnt vmcnt(0)" ::: "memory");
    }
    __builtin_amdgcn_s_barrier();                 // tile ti visible
    const bf16_t* Ash = &smem[c * 16384];
    const bf16_t* Bsh = Ash + 8192;
#pragma unroll
    for (int ks = 0; ks < 2; ++ks) {
      bf16x8 af[2], bfr[4];
#pragma unroll
      for (int mt = 0; mt < 2; ++mt)
        af[mt] = *(const bf16x8*)&Ash[(wm + mt * 16 + l16) * 64 + (((ks * 4 + lq) ^ swz) << 3)];
#pragma unroll
      for (int nt = 0; nt < 4; ++nt)
        bfr[nt] = *(const bf16x8*)&Bsh[(wn + nt * 16 + l16) * 64 + (((ks * 4 + lq) ^ swz) << 3)];
#pragma unroll
      for (int mt = 0; mt < 2; ++mt)
#pragma unroll
        for (int nt = 0; nt < 4; ++nt)
          acc[mt][nt] = MFMA_16x16x32(af[mt], bfr[nt], acc[mt][nt]);
    }
    __builtin_amdgcn_s_barrier();                 // buf c reads done
    c ^= 1;
  }

  if (TRANS) {
    bf16_t* sT = smem;
#pragma unroll
    for (int nt = 0; nt < 4; ++nt) {
      float bv = bias[n0 + wn + nt * 16 + l16];
#pragma unroll
      for (int mt = 0; mt < 2; ++mt) {
        bf16x4 p4;
#pragma unroll
        for (int r = 0; r < 4; ++r) p4[r] = (bf16_t)(acc[mt][nt][r] + bv);
        *(bf16x4*)&sT[(wn + nt * 16 + l16) * LDS_T + wm + mt * 16 + lq * 4] = p4;
      }
    }
    __syncthreads();
    int b = m0 >> 11, kp0 = m0 & (Lc - 1);
#pragma unroll
    for (int i = 0; i < 4; ++i) {
      int cidx = t + i * 512;
      int coln = cidx >> 4, cc = (cidx & 15) * 8;
      *(bf16x8*)&((bf16_t*)C)[((size_t)b * 1024 + n0 + coln) * (size_t)Lc + kp0 + cc] =
          *(const bf16x8*)&sT[coln * LDS_T + cc];
    }
  } else {
#pragma unroll
    for (int nt = 0; nt < 4; ++nt) {
      float bv = bias[n0 + wn + nt * 16 + l16];
#pragma unroll
      for (int mt = 0; mt < 2; ++mt) {
        int row = m0 + wm + mt * 16 + lq * 4;
        int col = n0 + wn + nt * 16 + l16;
#pragma unroll
        for (int r = 0; r < 4; ++r)
          C[(size_t)(row + r) * N + col] = (OutT)((acc[mt][nt][r] + bv) * scale);
      }
    }
  }
}

// standalone GEMM wrappers -------------------------------------------------
__global__ __launch_bounds__(512, 4)
void gemm_qkv_kernel(const bf16_t* __restrict__ Aq, const bf16_t* __restrict__ Ak,
                     const bf16_t* __restrict__ Av, const bf16_t* __restrict__ WT,
                     const float* __restrict__ bq, const float* __restrict__ bk,
                     const float* __restrict__ bv, bf16_t* __restrict__ Qp,
                     bf16_t* __restrict__ Kp, bf16_t* __restrict__ VpT) {
  __shared__ bf16_t smem[32768];
  int bid = blockIdx.x, seg = bid >> 9; bid &= 511;
  if (seg == 0)
    gemm_body<false, bf16_t>(Aq, WT, bq, Qp, QSCALE, bid, threadIdx.x, smem);
  else if (seg == 1)
    gemm_body<false, bf16_t>(Ak, WT + WSZ_E, bk, Kp, 1.0f, bid, threadIdx.x, smem);
  else
    gemm_body<true, bf16_t>(Av, WT + 2 * WSZ_E, bv, VpT, 1.0f, bid, threadIdx.x, smem);
}

__global__ __launch_bounds__(512, 4)
void gemm_qk_kernel(const bf16_t* __restrict__ Aq, const bf16_t* __restrict__ Ak,
                    const bf16_t* __restrict__ WT, const float* __restrict__ bq,
                    const float* __restrict__ bk, bf16_t* __restrict__ Qp,
                    bf16_t* __restrict__ Kp) {
  __shared__ bf16_t smem[32768];
  int bid = blockIdx.x, seg = bid >> 9; bid &= 511;
  if (seg == 0)
    gemm_body<false, bf16_t>(Aq, WT, bq, Qp, QSCALE, bid, threadIdx.x, smem);
  else
    gemm_body<false, bf16_t>(Ak, WT + WSZ_E, bk, Kp, 1.0f, bid, threadIdx.x, smem);
}

__global__ __launch_bounds__(512, 4)
void gemm_v_kernel(const bf16_t* __restrict__ Av, const bf16_t* __restrict__ Wt,
                   const float* __restrict__ bv, bf16_t* __restrict__ VpT) {
  __shared__ bf16_t smem[32768];
  gemm_body<true, bf16_t>(Av, Wt, bv, VpT, 1.0f, blockIdx.x, threadIdx.x, smem);
}

__global__ __launch_bounds__(512, 4)
void gemm_bf_kernel(const bf16_t* __restrict__ A, const bf16_t* __restrict__ Wt,
                    const float* __restrict__ bias, bf16_t* __restrict__ C,
                    float scale) {
  __shared__ bf16_t smem[32768];
  gemm_body<false, bf16_t>(A, Wt, bias, C, scale, blockIdx.x, threadIdx.x, smem);
}

__global__ __launch_bounds__(512, 4)
void gemm_o_kernel(const bf16_t* __restrict__ A, const bf16_t* __restrict__ Wt,
                   const float* __restrict__ bias, float* __restrict__ C) {
  __shared__ bf16_t smem[32768];
  gemm_body<false, float>(A, Wt, bias, C, 1.0f, blockIdx.x, threadIdx.x, smem);
}

// ---------------------------------------------------------------------------
// fp32-A TRANSOUT GEMM (small-ws fallback for v@Wv): reg-staged A with
// swizzled LDS write, single-buffered (R9-proven).
// ---------------------------------------------------------------------------
__global__ __launch_bounds__(512, 4)
void gemm_af32_kernel(const float* __restrict__ A, const bf16_t* __restrict__ Wt,
                      const float* __restrict__ bias, bf16_t* __restrict__ C) {
  constexpr int K = 1024, LDS_T = 136;
  __shared__ bf16_t smem[17408];
  bf16_t* Ash = smem;
  bf16_t* Bsh = smem + 8192;
  int bid = blockIdx.x;
  int xcd = bid & 7, slot = bid >> 3;
  int m0 = (xcd * 8 + (slot >> 3)) * 128;
  int n0 = (slot & 7) * 128;
  int t = threadIdx.x, lane = t & 63, w = t >> 6;
  int l16 = lane & 15, lq = lane >> 4;
  int wm = (w >> 1) * 32, wn = (w & 1) * 64;
  int srow = lane >> 3;
  int scol = ((lane & 7) ^ srow) << 3;
  int swz = l16 & 7;
  f32x4 acc[2][4] = {};

  for (int k0 = 0; k0 < K; k0 += 64) {
#pragma unroll
    for (int i = 0; i < 2; ++i) {
      int id = t + i * 512;
      int row = id >> 3, cc = (id & 7) * 8;
      f32x4 a0 = *(const f32x4*)&A[(size_t)(m0 + row) * K + k0 + cc];
      f32x4 a1 = *(const f32x4*)&A[(size_t)(m0 + row) * K + k0 + cc + 4];
      bf16x8 ah;
#pragma unroll
      for (int e = 0; e < 4; ++e) { ah[e] = (bf16_t)a0[e]; ah[4 + e] = (bf16_t)a1[e]; }
      *(bf16x8*)&Ash[row * 64 + (((cc >> 3) ^ (row & 7)) << 3)] = ah;
    }
#pragma unroll
    for (int j = 0; j < 2; ++j) {
      int r8 = (w * 2 + j) * 8;
      gload16(&Wt[(size_t)(n0 + r8 + srow) * K + k0 + scol], &Bsh[r8 * 64]);
    }
    __syncthreads();
#pragma unroll
    for (int ks = 0; ks < 2; ++ks) {
      bf16x8 af[2], bfr[4];
#pragma unroll
      for (int mt = 0; mt < 2; ++mt)
        af[mt] = *(const bf16x8*)&Ash[(wm + mt * 16 + l16) * 64 + (((ks * 4 + lq) ^ swz) << 3)];
#pragma unroll
      for (int nt = 0; nt < 4; ++nt)
        bfr[nt] = *(const bf16x8*)&Bsh[(wn + nt * 16 + l16) * 64 + (((ks * 4 + lq) ^ swz) << 3)];
#pragma unroll
      for (int mt = 0; mt < 2; ++mt)
#pragma unroll
        for (int nt = 0; nt < 4; ++nt)
          acc[mt][nt] = MFMA_16x16x32(af[mt], bfr[nt], acc[mt][nt]);
    }
    __syncthreads();
  }

  bf16_t* sT = smem;
#pragma unroll
  for (int nt = 0; nt < 4; ++nt) {
    float bv = bias[n0 + wn + nt * 16 + l16];
#pragma unroll
    for (int mt = 0; mt < 2; ++mt) {
      bf16x4 p4;
#pragma unroll
      for (int r = 0; r < 4; ++r) p4[r] = (bf16_t)(acc[mt][nt][r] + bv);
      *(bf16x4*)&sT[(wn + nt * 16 + l16) * LDS_T + wm + mt * 16 + lq * 4] = p4;
    }
  }
  __syncthreads();
  int b = m0 >> 11, kp0 = m0 & (Lc - 1);
#pragma unroll
  for (int i = 0; i < 4; ++i) {
    int cidx = t + i * 512;
    int coln = cidx >> 4, cc = (cidx & 15) * 8;
    *(bf16x8*)&C[((size_t)b * 1024 + n0 + coln) * (size_t)Lc + kp0 + cc] =
        *(const bf16x8*)&sT[coln * LDS_T + cc];
  }
}

// ---------------------------------------------------------------------------
// R10-proven attn body (73.6us): 64x64 tiles, 16x16 MFMA, 256-thr group.
// Swapped QK^T (S^T: col=q=l16, row=kpos); diag-peel causal mask; row-sum l
// via ones-MFMA (lane-local); Ps wave-private b64 writes -> no barrier
// between softmax and PV; K/V via global_load_lds + XOR swizzle.
// alds layout: Ks[4096] | Vt[4096] | Ps[64*72] = 12800 bf16 = 25600 B.
// __syncthreads() used -> in mega (512 thr) both groups MUST share px.
// ---------------------------------------------------------------------------
__device__ __forceinline__ void attn_body(
    const bf16_t* __restrict__ Qp, const bf16_t* __restrict__ Kp,
    const bf16_t* __restrict__ VpT, bf16_t* __restrict__ O,
    int bh, int px, int tid, bf16_t* __restrict__ alds) {
  constexpr int LDP = 72;
  bf16_t* Ks = alds;                 // [kpos][dh] swizzled 16B slots
  bf16_t* Vt = alds + 4096;          // [dh][kpos] swizzled 16B slots
  bf16_t* Ps = alds + 8192;          // [q][kpos]  padded
  int b = bh >> 4, h = bh & 15;
  int lane = tid & 63, w = tid >> 6;
  int l16 = lane & 15, lq = lane >> 4;
  int srow = lane >> 3;
  int scol = ((lane & 7) ^ srow) << 3;
  int swz = l16 & 7;
  const size_t base  = ((size_t)b * Lc) * Dc + h * 64;           // Q/K/O
  const size_t vbase = ((size_t)b * 1024 + h * 64) * (size_t)Lc; // VpT

  bf16x8 ones;
#pragma unroll
  for (int e = 0; e < 8; ++e) ones[e] = (bf16_t)1.0f;

#pragma unroll 1
  for (int phase = 0; phase < 2; ++phase) {
    int qt = phase ? 31 - px : px;
    int q0 = qt * 64;

    bf16x8 aq[2];
#pragma unroll
    for (int kd = 0; kd < 2; ++kd)
      aq[kd] = *(const bf16x8*)&Qp[base + (size_t)(q0 + w * 16 + l16) * Dc + kd * 32 + lq * 8];

    f32x4 oacc[4] = {};
    f32x4 lacc = {};
    int qrow = q0 + w * 16 + l16;               // this lane's q column in S^T

#pragma unroll 1
    for (int kt = 0; kt <= qt; ++kt) {
      int kbase = kt * 64;
#pragma unroll
      for (int j = 0; j < 2; ++j) {
        int r8 = (w * 2 + j) * 8;               // wave-uniform LDS base row
        int row = r8 + srow;
        gload16(&Kp[base + (size_t)(kbase + row) * Dc + scol], &Ks[r8 * 64]);
        gload16(&VpT[vbase + (size_t)row * Lc + kbase + scol], &Vt[r8 * 64]);
      }
      __syncthreads();

      // S^T = K Q^T (exp2 domain): D[kpos][q], col=l16 <-> q
      f32x4 sacc[4] = {};
#pragma unroll
      for (int ks = 0; ks < 2; ++ks) {
        bf16x8 bk[4];
#pragma unroll
        for (int nt = 0; nt < 4; ++nt)
          bk[nt] = *(const bf16x8*)&Ks[(nt * 16 + l16) * 64 + (((ks * 4 + lq) ^ swz) << 3)];
#pragma unroll
        for (int nt = 0; nt < 4; ++nt)
          sacc[nt] = MFMA_16x16x32(bk[nt], aq[ks], sacc[nt]);
      }

      // causal mask only on the diagonal tile (wave-uniform branch)
      if (kt == qt) {
#pragma unroll
        for (int nt = 0; nt < 4; ++nt)
#pragma unroll
          for (int r = 0; r < 4; ++r)
            if (kbase + nt * 16 + lq * 4 + r > qrow) sacc[nt][r] = -1.0e7f;
      }

      // softmax numerators; lane-local kpos run -> packed b64 Ps write
#pragma unroll
      for (int nt = 0; nt < 4; ++nt) {
        bf16x4 p4;
#pragma unroll
        for (int r = 0; r < 4; ++r) p4[r] = (bf16_t)exp2f(sacc[nt][r]);
        *(bf16x4*)&Ps[(w * 16 + l16) * LDP + nt * 16 + lq * 4] = p4;
      }
      // no barrier: Ps rows are wave-private, DS pipe in-order per wave

      // O += P V ; l += P @ ones (row-sum on the matrix pipe)
#pragma unroll
      for (int ks = 0; ks < 2; ++ks) {
        bf16x8 ap = *(const bf16x8*)&Ps[(w * 16 + l16) * LDP + ks * 32 + lq * 8];
        lacc = MFMA_16x16x32(ap, ones, lacc);
        bf16x8 bv2[4];
#pragma unroll
        for (int nt = 0; nt < 4; ++nt)
          bv2[nt] = *(const bf16x8*)&Vt[(nt * 16 + l16) * 64 + (((ks * 4 + lq) ^ swz) << 3)];
#pragma unroll
        for (int nt = 0; nt < 4; ++nt)
          oacc[nt] = MFMA_16x16x32(ap, bv2[nt], oacc[nt]);
      }
      __syncthreads();   // protect Ks/Vt before next stage
    }

    // l is lane-local (replicated across l16 by the ones-MFMA): no shuffles
#pragma unroll
    for (int r = 0; r < 4; ++r) {
      float inv = __builtin_amdgcn_rcpf(lacc[r]);
      int row = q0 + w * 16 + lq * 4 + r;
#pragma unroll
      for (int nt = 0; nt < 4; ++nt)
        O[base + (size_t)row * Dc + nt * 16 + l16] = (bf16_t)(oacc[nt][r] * inv);
    }
  }
}

__global__ __launch_bounds__(256, 4)
void attn_kernel(const bf16_t* __restrict__ Qp, const bf16_t* __restrict__ Kp,
                 const bf16_t* __restrict__ VpT, bf16_t* __restrict__ O) {
  __shared__ bf16_t alds[12800];
  int bid = blockIdx.x;
  int xcd = bid & 7, slot = bid >> 3;
  int bh = xcd * 8 + (slot >> 4);
  int px = slot & 15;
  attn_body(Qp, Kp, VpT, O, bh, px, threadIdx.x, alds);
}

// ---------------------------------------------------------------------------
// MEGAKERNEL: all 4 stages, one cooperative launch.  Grid 512 x 512 thr,
// 64KB LDS -> 2 blocks/CU co-resident (same per-stage occupancy as the
// separate launches).  grid.sync() between stages.
//   stage 1: qkv prep (4 items/thread) + 4x W transpose (2x256-thr groups)
//   stage 2: Q,K,V GEMMs (3 logical 512-blocks, sequential)
//   stage 3: attn (2x256-thr groups; both groups SAME px, different bh ->
//            identical barrier trip counts)
//   stage 4: O GEMM
// ---------------------------------------------------------------------------
__global__ __launch_bounds__(512, 4)
void mega_kernel(const float* __restrict__ q, const float* __restrict__ k,
                 const float* __restrict__ v,
                 const float* __restrict__ Wq, const float* __restrict__ bq,
                 const float* __restrict__ Wk, const float* __restrict__ bk,
                 const float* __restrict__ Wv, const float* __restrict__ bv,
                 const float* __restrict__ Wo, const float* __restrict__ bo,
                 bf16_t* __restrict__ Aq, bf16_t* __restrict__ Ak,
                 bf16_t* __restrict__ Av, bf16_t* __restrict__ WT,
                 bf16_t* __restrict__ Qp, bf16_t* __restrict__ Kp,
                 bf16_t* __restrict__ VpT, float* __restrict__ out) {
  __shared__ __align__(16) char msmem[65536];
  cg::grid_group grid = cg::this_grid();
  int phys = blockIdx.x;                          // 0..511
  int t = threadIdx.x;                            // 0..511

  // ---- stage 1: prep ----
  {
    int gtid = phys * 512 + t;
#pragma unroll 1
    for (int it = 0; it < 4; ++it)
      qkv_prep_body<true>(q, k, v, Aq, Ak, Av, gtid + it * 262144);
    int grp = t >> 8;
    int lg = phys * 2 + grp;                      // 0..1023
    int sel = lg >> 8;
    const float* W = (sel == 0) ? Wq : (sel == 1) ? Wk : (sel == 2) ? Wv : Wo;
    w_prep_body(W, WT + (size_t)sel * WSZ_E, t & 255, lg & 255,
                (float*)(msmem + grp * 16640));
  }
  __threadfence();
  grid.sync();

  // ---- stage 2: Q, K, V GEMMs ----
  gemm_body<false, bf16_t>(Aq, WT,            bq, Qp,  QSCALE, phys, t, (bf16_t*)msmem);
  __syncthreads();
  gemm_body<false, bf16_t>(Ak, WT + WSZ_E,    bk, Kp,  1.0f,   phys, t, (bf16_t*)msmem);
  __syncthreads();
  gemm_body<true,  bf16_t>(Av, WT + 2 * WSZ_E, bv, VpT, 1.0f,  phys, t, (bf16_t*)msmem);
  __threadfence();
  grid.sync();

  // ---- stage 3: attn (O aliases Qp; blocks read their Q rows first) ----
  {
    int grp = t >> 8, t256 = t & 255;
    int xcd = phys & 7, r = phys >> 3;            // r 0..63
    int px = r & 15, bp = r >> 4;                 // bp 0..3
    int bh = xcd * 8 + bp * 2 + grp;              // 0..63, same-XCD pair
    attn_body(Qp, Kp, VpT, Qp, bh, px, t256, (bf16_t*)(msmem + grp * 25600));
  }
  __threadfence();
  grid.sync();

  // ---- stage 4: O GEMM ----
  gemm_body<false, float>(Qp, WT + 3 * WSZ_E, bo, out, 1.0f, phys, t, (bf16_t*)msmem);
}

// ---------------------------------------------------------------------------
extern "C" void kernel_launch(void* const* d_in, const int* in_sizes, int n_in,
                              void* d_out, int out_size, void* d_ws, size_t ws_size,
                              hipStream_t stream) {
  (void)in_sizes; (void)n_in; (void)out_size;
  const float* q  = (const float*)d_in[0];
  const float* k  = (const float*)d_in[1];
  const float* v  = (const float*)d_in[2];
  // d_in[3] = padding: all false -> causal mask only
  const float* Wq = (const float*)d_in[4];
  const float* bq = (const float*)d_in[5];
  const float* Wk = (const float*)d_in[6];
  const float* bk = (const float*)d_in[7];
  const float* Wv = (const float*)d_in[8];
  const float* bv = (const float*)d_in[9];
  const float* Wo = (const float*)d_in[10];
  const float* bo = (const float*)d_in[11];
  float* out = (float*)d_out;

  char* ws = (char*)d_ws;
  constexpr size_t WT_B  = (size_t)Dc * Dc * 2;   // 2MB
  constexpr size_t MAT_B = (size_t)Mc * Dc * 2;   // 16MB

  if (ws_size >= 4 * WT_B + 6 * MAT_B) {
    // 104MB: WT x4 | Aq | Ak | Av | Qp | Kp | VpT.  Ob:=Qp.
    bf16_t* WT  = (bf16_t*)(ws);
    bf16_t* Aq  = (bf16_t*)(ws + 4 * WT_B);
    bf16_t* Ak  = (bf16_t*)(ws + 4 * WT_B + 1 * MAT_B);
    bf16_t* Av  = (bf16_t*)(ws + 4 * WT_B + 2 * MAT_B);
    bf16_t* Qp  = (bf16_t*)(ws + 4 * WT_B + 3 * MAT_B);
    bf16_t* Kp  = (bf16_t*)(ws + 4 * WT_B + 4 * MAT_B);
    bf16_t* VpT = (bf16_t*)(ws + 4 * WT_B + 5 * MAT_B);

    void* args[] = {&q, &k, &v, &Wq, &bq, &Wk, &bk, &Wv, &bv, &Wo, &bo,
                    &Aq, &Ak, &Av, &WT, &Qp, &Kp, &VpT, &out};
    hipError_t err = hipLaunchCooperativeKernel(
        (const void*)mega_kernel, dim3(512), dim3(512), args, 0u, stream);
    if (err == hipSuccess) return;
    (void)hipGetLastError();                       // clear; fall back

    prep_fused_kernel<<<5120, 256, 0, stream>>>(q, k, v, Aq, Ak, Av,
                                                Wq, Wk, Wv, Wo, WT);
    gemm_qkv_kernel<<<1536, 512, 0, stream>>>(Aq, Ak, Av, WT, bq, bk, bv,
                                              Qp, Kp, VpT);
    attn_kernel<<<1024, 256, 0, stream>>>(Qp, Kp, VpT, Qp);
    gemm_o_kernel<<<512, 512, 0, stream>>>(Qp, WT + 3 * WSZ_E, bo, out);
  } else if (ws_size >= 4 * WT_B + 5 * MAT_B) {
    // 88MB: WT x4 | Aq | Ak | Av | Qp | Kp.  VpT:=Aq (serial V gemm), Ob:=Qp.
    bf16_t* WT  = (bf16_t*)(ws);
    bf16_t* Aq  = (bf16_t*)(ws + 4 * WT_B);
    bf16_t* Ak  = (bf16_t*)(ws + 4 * WT_B + 1 * MAT_B);
    bf16_t* Av  = (bf16_t*)(ws + 4 * WT_B + 2 * MAT_B);
    bf16_t* Qp  = (bf16_t*)(ws + 4 * WT_B + 3 * MAT_B);
    bf16_t* Kp  = (bf16_t*)(ws + 4 * WT_B + 4 * MAT_B);
    bf16_t* VpT = Aq;   // Aq dead after QK gemm

    prep_fused_kernel<<<5120, 256, 0, stream>>>(q, k, v, Aq, Ak, Av,
                                                Wq, Wk, Wv, Wo, WT);
    gemm_qk_kernel<<<1024, 512, 0, stream>>>(Aq, Ak, WT, bq, bk, Qp, Kp);
    gemm_v_kernel<<<512, 512, 0, stream>>>(Av, WT + 2 * WSZ_E, bv, VpT);
    attn_kernel<<<1024, 256, 0, stream>>>(Qp, Kp, VpT, Qp);
    gemm_o_kernel<<<512, 512, 0, stream>>>(Qp, WT + 3 * WSZ_E, bo, out);
  } else {
    // 50MB: WT | Aq | Ak | Qp.  Kp:=Aq, VpT:=Ak, Ob:=Qp.
    bf16_t* WT  = (bf16_t*)(ws);
    bf16_t* Aq  = (bf16_t*)(ws + WT_B);
    bf16_t* Ak  = (bf16_t*)(ws + WT_B + 1 * MAT_B);
    bf16_t* Qp  = (bf16_t*)(ws + WT_B + 2 * MAT_B);
    bf16_t* Kp  = Aq;
    bf16_t* VpT = Ak;

    qkv_prep_kernel<false><<<4096, 256, 0, stream>>>(q, k, nullptr, Aq, Ak, nullptr);
    w_prep_kernel<<<256, 256, 0, stream>>>(Wq, WT);
    gemm_bf_kernel<<<512, 512, 0, stream>>>(Aq, WT, bq, Qp, QSCALE);
    w_prep_kernel<<<256, 256, 0, stream>>>(Wk, WT);
    gemm_bf_kernel<<<512, 512, 0, stream>>>(Ak, WT, bk, Kp, 1.0f);
    w_prep_kernel<<<256, 256, 0, stream>>>(Wv, WT);
    gemm_af32_kernel<<<512, 512, 0, stream>>>(v, WT, bv, VpT);
    attn_kernel<<<1024, 256, 0, stream>>>(Qp, Kp, VpT, Qp);
    w_prep_kernel<<<256, 256, 0, stream>>>(Wo, WT);
    gemm_o_kernel<<<512, 512, 0, stream>>>(Qp, WT, bo, out);
  }
}